// Round 7
// baseline (51.510 us; speedup 1.0000x reference)
//
#include <hip/hip_runtime.h>
#include <math.h>

#define C      128
#define CAPLG  12
#define CAP    (1 << CAPLG)      // bucket capacity per class (max count ~2300 << 4096)
#define SPLIT  16                // blocks per class in main pass
#define NMB    (C * SPLIT)       // 2048 main blocks
#define SPB    1024              // samples per scatter block
#define CSTR   16                // cursor stride in ints -> one 64B line per class
#define PBS    260               // partial row stride: sp[128] sln[128] pos pad
#define LN2F   0.69314718056f

__device__ __forceinline__ float fast_rcp(float x) { return __builtin_amdgcn_rcpf(x); }

// ---------------------------------------------------------------------------
// Bucketed counting-sort scatter: int4 target loads, LDS rank, one global
// range-reservation atomic per class per block (padded lines).
__global__ __launch_bounds__(256)
void scatter_kernel(const int* __restrict__ tgt, int* __restrict__ cursor2,
                    int* __restrict__ perm, int B) {
    __shared__ int lcur[C];
    __shared__ int sbase[C];
    if (threadIdx.x < C) lcur[threadIdx.x] = 0;
    __syncthreads();
    const int base = blockIdx.x * SPB + threadIdx.x * 4;
    int t0 = -1, t1 = -1, t2 = -1, t3 = -1;
    if (base + 3 < B) {
        int4 t4 = *reinterpret_cast<const int4*>(tgt + base);
        t0 = t4.x; t1 = t4.y; t2 = t4.z; t3 = t4.w;
    } else {
        if (base     < B) t0 = tgt[base];
        if (base + 1 < B) t1 = tgt[base + 1];
        if (base + 2 < B) t2 = tgt[base + 2];
        if (base + 3 < B) t3 = tgt[base + 3];
    }
    int r0 = (t0 >= 0) ? atomicAdd(&lcur[t0], 1) : 0;
    int r1 = (t1 >= 0) ? atomicAdd(&lcur[t1], 1) : 0;
    int r2 = (t2 >= 0) ? atomicAdd(&lcur[t2], 1) : 0;
    int r3 = (t3 >= 0) ? atomicAdd(&lcur[t3], 1) : 0;
    __syncthreads();
    if (threadIdx.x < C)
        sbase[threadIdx.x] = atomicAdd(&cursor2[threadIdx.x * CSTR], lcur[threadIdx.x]);
    __syncthreads();
    if (t0 >= 0) perm[(t0 << CAPLG) + sbase[t0] + r0] = base;
    if (t1 >= 0) perm[(t1 << CAPLG) + sbase[t1] + r1] = base + 1;
    if (t2 >= 0) perm[(t2 << CAPLG) + sbase[t2] + r2] = base + 2;
    if (t3 >= 0) perm[(t3 << CAPLG) + sbase[t3] + r3] = base + 3;
}

// ---------------------------------------------------------------------------
// Main pass: block = (class k, split p). One row per iteration, float2/lane
// (64 lanes x 2 cols = 512B row), depth-3 rolling prefetch. Wave range <= 64
// rows (CAP/SPLIT/4 = 64), so ONE perm tile load serves the whole wave.
// Epilogue: LDS cross-wave reduce, row-major coalesced partial write
// (block-local -> no false sharing).
__global__ __launch_bounds__(256)
void main_kernel(const float* __restrict__ x, const int* __restrict__ perm,
                 const int* __restrict__ cursor2, float* __restrict__ partial) {
    const int k = blockIdx.x >> 4;            // / SPLIT
    const int p = blockIdx.x & (SPLIT - 1);
    const int n = min(cursor2[k * CSTR], CAP);
    const int chunk = (n + SPLIT - 1) >> 4;
    const int s0 = min(p * chunk, n);
    const int s1 = min(s0 + chunk, n);

    const int tid  = threadIdx.x;
    const int wave = tid >> 6;
    const int lane = tid & 63;
    const bool poslane = (lane == (k >> 1));
    const int  kpar = k & 1;

    const int wlen = (s1 - s0 + 3) >> 2;      // <= 64
    const int ws0  = s0 + wave * wlen;
    const int ws1  = min(ws0 + wlen, s1);
    const int wn   = (ws1 > ws0) ? (ws1 - ws0) : 0;

    const int* bperm = perm + (k << CAPLG);
    const int pv = (lane < wn) ? bperm[ws0 + lane] : 0;   // whole wave range, 1 load

    float ap0 = 0.f, ap1 = 0.f, sx0 = 0.f, sx1 = 0.f, sl0 = 0.f, sl1 = 0.f;
    float apos = 0.f;

    if (wn > 0) {
        const float* xl = x + 2 * lane;
        float2 b0 = *reinterpret_cast<const float2*>(xl + (size_t)__shfl(pv, 0) * C);
        float2 b1 = *reinterpret_cast<const float2*>(xl + (size_t)__shfl(pv, min(1, wn - 1)) * C);
        float2 b2 = *reinterpret_cast<const float2*>(xl + (size_t)__shfl(pv, min(2, wn - 1)) * C);
        for (int j = 0; j < wn; ++j) {
            float2 cur = b0; b0 = b1; b1 = b2;
            if (j + 3 < wn)
                b2 = *reinterpret_cast<const float2*>(xl + (size_t)__shfl(pv, j + 3) * C);
            float e0 = __expf(-cur.x), u0 = 1.f + e0, l0 = __log2f(u0);
            float e1 = __expf(-cur.y), u1 = 1.f + e1, l1 = __log2f(u1);
            ap0 += fast_rcp(u0); sx0 += cur.x; sl0 += l0;
            ap1 += fast_rcp(u1); sx1 += cur.y; sl1 += l1;
            if (poslane) apos += kpar ? l1 : l0;
        }
    }

    // ---- cross-wave LDS reduce (plain float2 writes, no atomics) ----
    __shared__ __align__(8) float sP[4][C];
    __shared__ __align__(8) float sX[4][C];
    __shared__ __align__(8) float sL[4][C];
    __shared__ float sPos[4];
    *reinterpret_cast<float2*>(&sP[wave][2 * lane]) = make_float2(ap0, ap1);
    *reinterpret_cast<float2*>(&sX[wave][2 * lane]) = make_float2(sx0, sx1);
    *reinterpret_cast<float2*>(&sL[wave][2 * lane]) = make_float2(sl0, sl1);
    if (poslane) sPos[wave] = apos;
    __syncthreads();

    float* mine = partial + (size_t)blockIdx.x * PBS;
    if (tid < C) {                       // sum_probs col tid
        mine[tid] = sP[0][tid] + sP[1][tid] + sP[2][tid] + sP[3][tid];
    } else {                             // sum_logneg: -sum(x) - ln2*sum(log2(1+e))
        const int t = tid - C;
        float sx = sX[0][t] + sX[1][t] + sX[2][t] + sX[3][t];
        float sl = sL[0][t] + sL[1][t] + sL[2][t] + sL[3][t];
        mine[C + t] = -sx - LN2F * sl;
    }
    if (tid == 0)
        mine[256] = -LN2F * (sPos[0] + sPos[1] + sPos[2] + sPos[3]);
}

// ---------------------------------------------------------------------------
// Fused finalize: block k. Phase 1: thread j (0..127) gathers class j's 16
// split-partials at column k (strided loads, L2/L3-hot, 32 independent
// loads/thread). Phase 2: wave 0 masked softmax + ticket; last block sums.
__global__ __launch_bounds__(128)
void finalize_kernel(const float* __restrict__ partial, const int* __restrict__ cursor2,
                     float* __restrict__ colpart, int* __restrict__ ticket,
                     float* __restrict__ out) {
    const int k   = blockIdx.x;
    const int tid = threadIdx.x;

    __shared__ float spcol[C], slcol[C];
    __shared__ float sposr[SPLIT];

    {   // phase 1
        const int j = tid;
        const float* rowp = partial + (size_t)j * SPLIT * PBS;
        float aP = 0.f, aL = 0.f;
#pragma unroll
        for (int q = 0; q < SPLIT; ++q) {
            aP += rowp[q * PBS + k];
            aL += rowp[q * PBS + C + k];
        }
        spcol[j] = aP; slcol[j] = aL;
        if (tid < SPLIT)
            sposr[tid] = partial[((size_t)k * SPLIT + tid) * PBS + 256];
    }
    __syncthreads();

    // phase 2: wave 0, lane l covers rows l and l+64
    if (tid < 64) {
        const int l = tid, j0 = l, j1 = l + 64;
        const float c0 = (float)cursor2[j0 * CSTR];
        const float c1 = (float)cursor2[j1 * CSTR];
        const bool  v0 = (j0 != k) && (c0 > 0.f);
        const bool  v1 = (j1 != k) && (c1 > 0.f);
        const float x0 = v0 ? spcol[j0] / c0 : -INFINITY;
        const float x1 = v1 ? spcol[j1] / c1 : -INFINITY;

        float m = fmaxf(x0, x1);
#pragma unroll
        for (int d = 1; d < 64; d <<= 1) m = fmaxf(m, __shfl_xor(m, d));

        float w0 = v0 ? __expf(x0 - m) : 0.f;
        float w1 = v1 ? __expf(x1 - m) : 0.f;
        float den = w0 + w1;
        float num = (v0 ? w0 * (slcol[j0] / c0) : 0.f)
                  + (v1 ? w1 * (slcol[j1] / c1) : 0.f);
#pragma unroll
        for (int d = 1; d < 64; d <<= 1) { den += __shfl_xor(den, d); num += __shfl_xor(num, d); }

        int last = 0;
        if (l == 0) {
            float colneg = (den > 0.f) ? num / den : 0.f;
            float ck     = (float)cursor2[k * CSTR];
            float ps     = 0.f;
#pragma unroll
            for (int q = 0; q < SPLIT; ++q) ps += sposr[q];
            float pk = (ck > 0.f) ? ps / ck : 0.f;
            colpart[k] = colneg + pk;
            __threadfence();                       // publish colpart before ticket
            last = (atomicAdd(ticket, 1) == C - 1);
        }
        last = __shfl(last, 0);
        if (last) {                                // last block: global sum -> out
            __threadfence();                       // acquire others' colpart
            float s = colpart[l] + colpart[l + 64];
#pragma unroll
            for (int d = 1; d < 64; d <<= 1) s += __shfl_xor(s, d);
            if (l == 0) out[0] = -s;
        }
    }
}

// ---------------------------------------------------------------------------
extern "C" void kernel_launch(void* const* d_in, const int* in_sizes, int n_in,
                              void* d_out, int out_size, void* d_ws, size_t ws_size,
                              hipStream_t stream) {
    const float* x   = (const float*)d_in[0];
    const int*   tgt = (const int*)d_in[1];
    const int B = in_sizes[1];

    int*   cursor2 = (int*)d_ws;                          // C*CSTR ints
    int*   ticket  = cursor2 + C * CSTR;                  // 1 int (own line)
    int*   perm    = cursor2 + C * CSTR + CSTR;           // C*CAP ints
    float* partial = (float*)(perm + C * CAP);            // NMB*PBS floats
    float* colpart = partial + (size_t)NMB * PBS;         // C floats

    hipMemsetAsync(cursor2, 0, (C * CSTR + CSTR) * sizeof(int), stream);
    scatter_kernel<<<(B + SPB - 1) / SPB, 256, 0, stream>>>(tgt, cursor2, perm, B);
    main_kernel<<<NMB, 256, 0, stream>>>(x, perm, cursor2, partial);
    finalize_kernel<<<C, 128, 0, stream>>>(partial, cursor2, colpart, ticket, (float*)d_out);
}